// Round 2
// baseline (944.284 us; speedup 1.0000x reference)
//
#include <hip/hip_runtime.h>
#include <hip/hip_bf16.h>

typedef __hip_bfloat16 bf16;

static __device__ __forceinline__ float b2f(bf16 h) { return __bfloat162float(h); }
static __device__ __forceinline__ float us2f(unsigned short u) {
    union { unsigned short u; bf16 h; } cv; cv.u = u; return __bfloat162float(cv.h);
}
static __device__ __forceinline__ unsigned short f2us(float f) {
    __hip_bfloat16 h = __float2bfloat16(f);
    union { __hip_bfloat16 h; unsigned short u; } cv; cv.h = h; return cv.u;
}

// ws layout (floats):
//   q  : [64][32][1024]  at 0          (2,097,152)
//   k  : [16][32][1024]  at 2,097,152  (  524,288)
//   vT : [16][1024][64]  at 2,621,440  (1,048,576)
//   flags (int[4])       at 3,670,016
#define Q_OFF 0
#define K_OFF 2097152
#define V_OFF 2621440
#define FLG_OFF 3670016

// ---------------- Kernel 0: dtype detection ----------------
// Interpreting a float32 buffer's even 16-bit halves as bf16 gives garbage
// exponents (|x|>1e4 or NaN with p~0.45/elem). A real bf16 buffer of
// N(0,1)-scale data never exceeds 1e4. flags[b] = 1 means "buffer b is f32".
__global__ __launch_bounds__(256) void detect_kernel(
    const void* inp, const void* dyn, const void* wq, int* flags)
{
    __shared__ int bad;
    if (threadIdx.x == 0) bad = 0;
    __syncthreads();
    const void* bufs[3] = { inp, dyn, wq };
    const int nscan[3] = { 2048, 2048, 1024 };   // even-index checks (safe in both interps)
    const int b = blockIdx.x;
    const unsigned short* u = (const unsigned short*)bufs[b];
    int myBad = 0;
    for (int i = threadIdx.x; i < nscan[b]; i += 256) {
        float x = us2f(u[i * 2]);
        if (!(x > -1e4f && x < 1e4f)) myBad++;   // NaN also lands here
    }
    atomicAdd(&bad, myBad);
    __syncthreads();
    if (threadIdx.x == 0) flags[b] = (bad >= 4) ? 1 : 0;
}

// ---------------- Kernel 1: projections q,k,v ----------------
// blocks 0..63   : k+v for 16 xin-batches (4 blocks of 256 n each)
// blocks 64..319 : q for 64 batches (4 blocks of 256 n each)
__global__ __launch_bounds__(256) void proj_kernel(
    const void* __restrict__ inputs, const void* __restrict__ dyn,
    const void* __restrict__ wq, const void* __restrict__ bq,
    const void* __restrict__ wk, const void* __restrict__ bk,
    const void* __restrict__ wv, const void* __restrict__ bv,
    float* __restrict__ ws, const int* __restrict__ flags)
{
    __shared__ float sW[6240];      // wk(2048)+wv(4096)+bk(32)+bv(64)  OR wq(2048)+bq(32)
    __shared__ float sV[256 * 65];  // v transpose staging (pad 65 -> conflict-free)
    const int t = threadIdx.x;
    const int blk = blockIdx.x;
    const int fin  = flags[0];
    const int fdyn = flags[1];
    const int fw   = flags[2];
    float* qws = ws + Q_OFF;
    float* kws = ws + K_OFF;
    float* vws = ws + V_OFF;

    if (blk < 64) {
        const int ib = blk >> 2;
        const int n = ((blk & 3) << 8) + t;
        if (fw) {
            const float* wkf = (const float*)wk; const float* wvf = (const float*)wv;
            const float* bkf = (const float*)bk; const float* bvf = (const float*)bv;
            for (int i = t; i < 2048; i += 256) sW[i] = wkf[i];
            for (int i = t; i < 4096; i += 256) sW[2048 + i] = wvf[i];
            if (t < 32) sW[6144 + t] = bkf[t];
            else if (t >= 64 && t < 128) sW[6176 + (t - 64)] = bvf[t - 64];
        } else {
            const bf16* wkb = (const bf16*)wk; const bf16* wvb = (const bf16*)wv;
            const bf16* bkb = (const bf16*)bk; const bf16* bvb = (const bf16*)bv;
            for (int i = t; i < 2048; i += 256) sW[i] = b2f(wkb[i]);
            for (int i = t; i < 4096; i += 256) sW[2048 + i] = b2f(wvb[i]);
            if (t < 32) sW[6144 + t] = b2f(bkb[t]);
            else if (t >= 64 && t < 128) sW[6176 + (t - 64)] = b2f(bvb[t - 64]);
        }
        __syncthreads();

        float ak[32], av[64];
        #pragma unroll
        for (int o = 0; o < 32; o++) ak[o] = sW[6144 + o];
        #pragma unroll
        for (int d = 0; d < 64; d++) av[d] = sW[6176 + d];

        const int xoff = ib * 65536 + n;
        if (fin) {
            const float* xp = (const float*)inputs + xoff;
            for (int c = 0; c < 64; c++) {
                float x = xp[c << 10];
                #pragma unroll
                for (int o = 0; o < 32; o++) ak[o] = fmaf(sW[(o << 6) + c], x, ak[o]);
                #pragma unroll
                for (int d = 0; d < 64; d++) av[d] = fmaf(sW[2048 + (d << 6) + c], x, av[d]);
            }
        } else {
            const bf16* xp = (const bf16*)inputs + xoff;
            for (int c = 0; c < 64; c++) {
                float x = b2f(xp[c << 10]);
                #pragma unroll
                for (int o = 0; o < 32; o++) ak[o] = fmaf(sW[(o << 6) + c], x, ak[o]);
                #pragma unroll
                for (int d = 0; d < 64; d++) av[d] = fmaf(sW[2048 + (d << 6) + c], x, av[d]);
            }
        }
        // k[ib][o][n] : coalesced per o
        float* kb = kws + ib * 32768 + n;
        #pragma unroll
        for (int o = 0; o < 32; o++) kb[o << 10] = ak[o];
        // vT[ib][n][d] via LDS transpose
        #pragma unroll
        for (int d = 0; d < 64; d++) sV[t * 65 + d] = av[d];
        __syncthreads();
        float* vb = vws + ib * 65536 + ((blk & 3) << 14);
        for (int i = 0; i < 64; i++) {
            int g = (i << 8) + t;          // 0..16383 coalesced
            int nn = g >> 6, dd = g & 63;
            vb[g] = sV[nn * 65 + dd];
        }
    } else {
        const int idx = blk - 64;
        const int b = idx >> 2;
        const int n = ((idx & 3) << 8) + t;
        if (fw) {
            const float* wqf = (const float*)wq; const float* bqf = (const float*)bq;
            for (int i = t; i < 2048; i += 256) sW[i] = wqf[i];
            if (t < 32) sW[2048 + t] = bqf[t];
        } else {
            const bf16* wqb = (const bf16*)wq; const bf16* bqb = (const bf16*)bq;
            for (int i = t; i < 2048; i += 256) sW[i] = b2f(wqb[i]);
            if (t < 32) sW[2048 + t] = b2f(bqb[t]);
        }
        __syncthreads();

        float aq[32];
        #pragma unroll
        for (int o = 0; o < 32; o++) aq[o] = sW[2048 + o];
        const int xoff = b * 65536 + n;
        if (fdyn) {
            const float* xp = (const float*)dyn + xoff;
            for (int c = 0; c < 64; c++) {
                float x = xp[c << 10];
                #pragma unroll
                for (int o = 0; o < 32; o++) aq[o] = fmaf(sW[(o << 6) + c], x, aq[o]);
            }
        } else {
            const bf16* xp = (const bf16*)dyn + xoff;
            for (int c = 0; c < 64; c++) {
                float x = b2f(xp[c << 10]);
                #pragma unroll
                for (int o = 0; o < 32; o++) aq[o] = fmaf(sW[(o << 6) + c], x, aq[o]);
            }
        }
        // q[b][o][n] : coalesced per o
        float* qb = qws + b * 32768 + n;
        #pragma unroll
        for (int o = 0; o < 32; o++) qb[o << 10] = aq[o];
    }
}

// ---------------- Kernel 2: energy -> softmax -> attn out + out GEMM ----------------
// grid: 64 batches x 64 row-tiles (16 rows each). block 256.
#define ES 1032   // padded E row stride (floats)
__global__ __launch_bounds__(256) void attn_kernel(
    const float* __restrict__ ws, const int* __restrict__ flags, void* __restrict__ dout)
{
    __shared__ float E[16 * ES];    // 66,048 B; reused as reduction buf in out phase
    __shared__ float qL[16 * 32];
    __shared__ float red[256];
    __shared__ float Mv[16];
    __shared__ float inv[16];

    const int t  = threadIdx.x;
    const int bx = blockIdx.x;
    const int b  = bx >> 6;
    const int rt = bx & 63;
    const int r0 = rt << 4;
    const int ib = ((b >> 5) << 3) + (b & 7);   // xin batch index
    const int fo = flags[0] & flags[1] & flags[2];  // 1 = f32 output, else bf16

    const float* qws = ws + Q_OFF;
    const float* kws = ws + K_OFF;
    const float* vws = ws + V_OFF;

    // q tile: qL[r][o] <- q[b][o][r0+r]
    {
        int p = t;
        #pragma unroll
        for (int rep = 0; rep < 2; rep++, p += 256) {
            int o = p >> 4, r = p & 15;
            qL[r * 32 + o] = qws[b * 32768 + (o << 10) + r0 + r];
        }
    }
    __syncthreads();

    // energy: E[r][m] = sum_o qL[r][o] * k[ib][o][m]
    {
        const float* kp = kws + ib * 32768;
        for (int c = 0; c < 4; c++) {
            const int m = (c << 8) + t;
            float kv[32];
            #pragma unroll
            for (int o = 0; o < 32; o++) kv[o] = kp[(o << 10) + m];
            #pragma unroll
            for (int r = 0; r < 16; r++) {
                float e = 0.f;
                #pragma unroll
                for (int o = 0; o < 32; o++) e = fmaf(qL[r * 32 + o], kv[o], e);
                E[r * ES + m] = e;
            }
        }
    }
    __syncthreads();

    // softmax over each row (16 threads per row, strided columns)
    {
        const int r = t >> 4, j = t & 15;
        float lmax = -1e30f;
        for (int i = 0; i < 64; i++) lmax = fmaxf(lmax, E[r * ES + j + (i << 4)]);
        red[t] = lmax;
        __syncthreads();
        if (t < 16) {
            float mx = red[t * 16];
            for (int i = 1; i < 16; i++) mx = fmaxf(mx, red[t * 16 + i]);
            Mv[t] = mx;
        }
        __syncthreads();
        const float M = Mv[r];
        float lsum = 0.f;
        for (int i = 0; i < 64; i++) {
            int idx = r * ES + j + (i << 4);
            float p = __expf(E[idx] - M);
            E[idx] = p;
            lsum += p;
        }
        red[t] = lsum;
        __syncthreads();
        if (t < 16) {
            float s = 0.f;
            for (int i = 0; i < 16; i++) s += red[t * 16 + i];
            inv[t] = 1.0f / s;
        }
        __syncthreads();
    }

    // normalize in LDS + write attn (coalesced)
    if (fo == 0) {
        unsigned int* ap = (unsigned int*)((bf16*)dout + 4194304 + (size_t)b * 1048576 + (size_t)r0 * 1024);
        for (int r = 0; r < 16; r++) {
            const float iv = inv[r];
            #pragma unroll
            for (int c = 0; c < 2; c++) {
                const int m0 = (t << 1) + (c << 9);
                float2 f = *reinterpret_cast<const float2*>(&E[r * ES + m0]);
                f.x *= iv; f.y *= iv;
                *reinterpret_cast<float2*>(&E[r * ES + m0]) = f;
                unsigned int pk = ((unsigned int)f2us(f.y) << 16) | f2us(f.x);
                ap[(r << 9) + (m0 >> 1)] = pk;
            }
        }
    } else {
        float* ap = (float*)dout + 4194304 + (size_t)b * 1048576 + (size_t)r0 * 1024;
        for (int r = 0; r < 16; r++) {
            const float iv = inv[r];
            #pragma unroll
            for (int c = 0; c < 2; c++) {
                const int m0 = (t << 1) + (c << 9);
                float2 f = *reinterpret_cast<const float2*>(&E[r * ES + m0]);
                f.x *= iv; f.y *= iv;
                *reinterpret_cast<float2*>(&E[r * ES + m0]) = f;
                *reinterpret_cast<float2*>(&ap[(r << 10) + m0]) = f;
            }
        }
    }
    __syncthreads();

    // out GEMM: out[d][r0+r] = sum_m E[r][m] * vT[ib][m][d]
    {
        const int d = t & 63, g = t >> 6;
        float acc[16];
        #pragma unroll
        for (int r = 0; r < 16; r++) acc[r] = 0.f;
        const float* vp = vws + ib * 65536 + d;
        const int mbase = g << 8;
        for (int mq = 0; mq < 256; mq += 4) {
            const int m = mbase + mq;
            float v0 = vp[(m)     << 6];
            float v1 = vp[(m + 1) << 6];
            float v2 = vp[(m + 2) << 6];
            float v3 = vp[(m + 3) << 6];
            #pragma unroll
            for (int r = 0; r < 16; r++) {
                const float4 e4 = *reinterpret_cast<const float4*>(&E[r * ES + m]);
                acc[r] = fmaf(e4.x, v0, fmaf(e4.y, v1, fmaf(e4.z, v2, fmaf(e4.w, v3, acc[r]))));
            }
        }
        __syncthreads();            // all E reads done, safe to alias
        float* buf = E;             // buf[g][d][r] with stride d*17 (2-way max)
        #pragma unroll
        for (int r = 0; r < 16; r++) buf[g * 1088 + d * 17 + r] = acc[r];
        __syncthreads();
    }

    // reduce 4 partials + write out (coalesced)
    {
        const int d = t >> 2, rb = (t & 3) << 2;
        const float* buf = E;
        float s[4];
        #pragma unroll
        for (int k = 0; k < 4; k++) {
            const int off = d * 17 + rb + k;
            s[k] = buf[off] + buf[1088 + off] + buf[2176 + off] + buf[3264 + off];
        }
        if (fo == 0) {
            ushort4 pk;
            pk.x = f2us(s[0]); pk.y = f2us(s[1]); pk.z = f2us(s[2]); pk.w = f2us(s[3]);
            *reinterpret_cast<ushort4*>((bf16*)dout + (size_t)b * 65536 + (d << 10) + r0 + rb) = pk;
        } else {
            float4 f4;
            f4.x = s[0]; f4.y = s[1]; f4.z = s[2]; f4.w = s[3];
            *reinterpret_cast<float4*>((float*)dout + (size_t)b * 65536 + (d << 10) + r0 + rb) = f4;
        }
    }
}

extern "C" void kernel_launch(void* const* d_in, const int* in_sizes, int n_in,
                              void* d_out, int out_size, void* d_ws, size_t ws_size,
                              hipStream_t stream) {
    float* ws = (float*)d_ws;
    int* flags = (int*)(ws + FLG_OFF);

    detect_kernel<<<3, 256, 0, stream>>>(d_in[0], d_in[1], d_in[2], flags);
    proj_kernel<<<320, 256, 0, stream>>>(d_in[0], d_in[1], d_in[2], d_in[3],
                                         d_in[4], d_in[5], d_in[6], d_in[7],
                                         ws, flags);
    attn_kernel<<<4096, 256, 0, stream>>>(ws, flags, d_out);
}